// Round 5
// baseline (897.955 us; speedup 1.0000x reference)
//
#include <hip/hip_runtime.h>

// Problem constants (from reference):
//   B=100000, R1=1, N1=200, N2=200, N3=50, R2=32
//   TT_core: (1,200,200,50,32) f32  = 64,000,000 elems (256 MB)
//   K1,K2: (200,200) f32; K3: (50,50) f32; indices: (B,3) int (values in [0,50))
//   out = (T3 gathered)[B,1,32] (3.2M f32), reg = T3*TT (64M f32)
// d_out layout: [0,3.2M) out, [3.2M, 67.2M) reg.
//
// Round-5: k_mfma_contract restructured for latency (round-4 evidence:
// MfmaUtil 13%, VALUBusy 14%, Occ 20% -> 2 waves/SIMD, no prefetch).
//   - wave n-width 16 (acc 52 regs, ~5 waves/SIMD on unified VGPR/AGPR file)
//   - exact grids -> zero bounds predication; k-tail = one uniform branch
//   - depth-1 software pipeline (xa/xb static double buffer)

typedef float  f32x4  __attribute__((ext_vector_type(4)));
typedef short  short8 __attribute__((ext_vector_type(8)));
typedef unsigned short u16;
typedef unsigned int   u32;

#define N12   200
#define N3    50
#define R2    32
#define SJK   320000          // stride of i in TT == N2*N3*R2; also stride of a in T1
#define SKS   1600            // stride of j / b  == N3*R2
#define NTOT  64000000
#define OUT_ELEMS 3200000     // B*32
#define APAD  208             // padded rows of K matrices (13 * 16)
#define KPAD  224             // padded contraction dim (7 * 32)

__device__ __forceinline__ u16 f2bf(float x) {
  u32 u = __builtin_bit_cast(u32, x);
  u += 0x7fffu + ((u >> 16) & 1u);      // round-to-nearest-even
  return (u16)(u >> 16);
}
__device__ __forceinline__ float bf2f(u16 h) {
  return __builtin_bit_cast(float, (u32)h << 16);
}

// ---------------- prep: split K1,K2 into padded bf16 hi/lo [208][224] ------
// khi/klo each hold two matrices back-to-back: K1 at 0, K2 at APAD*KPAD.
__global__ __launch_bounds__(256) void k_prep(
    const float* __restrict__ K1, const float* __restrict__ K2,
    u16* __restrict__ khi, u16* __restrict__ klo) {
  int t = blockIdx.x * 256 + threadIdx.x;
  const int total = APAD * KPAD;
  if (t >= 2 * total) return;
  const float* src = (t < total) ? K1 : K2;
  int tt = (t < total) ? t : t - total;
  int r = tt / KPAD, c = tt % KPAD;
  float x = (r < N12 && c < N12) ? src[r * N12 + c] : 0.f;
  u16 h = f2bf(x);
  khi[t] = h;
  klo[t] = f2bf(x - bf2f(h));
}

// ---------------- MFMA contraction: D[row,n] = sum_k K[row,k] * B[k,n] -----
// A = prepped hi/lo bf16 [APAD][KPAD] (split product: hi*hi + hi*lo + lo*hi).
// Per wave: n-subtile of 16, ALL 13 row-tiles in accumulators; B read once.
// Pipeline: loads for step ks+1 issued before the MFMA cluster of step ks.
// Grids are exact (n-blocks of 64 divide both 320000 and 1600) -> no bounds
// checks anywhere in the hot loop.
#define LOADB(KS, X)                                                         \
  { _Pragma("unroll")                                                        \
    for (int e = 0; e < 8; ++e) X[e] = bp[(long)((KS)*32 + kq + e) * ldB]; }

#define MFMA_STAGE(KS, X)                                                    \
  { short8 bh, bl;                                                           \
    _Pragma("unroll")                                                        \
    for (int e = 0; e < 8; ++e) {                                            \
      u16 h = f2bf(X[e]);                                                    \
      bh[e] = (short)h;                                                      \
      bl[e] = (short)f2bf(X[e] - bf2f(h));                                   \
    }                                                                        \
    _Pragma("unroll")                                                        \
    for (int t = 0; t < 13; ++t) {                                           \
      const int aoff = (t * 16 + l15) * KPAD + (KS)*32 + kq;                 \
      short8 ah = *(const short8*)(Ahi + aoff);                              \
      short8 al = *(const short8*)(Alo + aoff);                              \
      acc[t] = __builtin_amdgcn_mfma_f32_16x16x32_bf16(ah, bh, acc[t], 0,0,0); \
      acc[t] = __builtin_amdgcn_mfma_f32_16x16x32_bf16(al, bh, acc[t], 0,0,0); \
      acc[t] = __builtin_amdgcn_mfma_f32_16x16x32_bf16(ah, bl, acc[t], 0,0,0); \
    } }

__global__ __launch_bounds__(256) void k_mfma_contract(
    const float* __restrict__ Bsrc, const u16* __restrict__ Ahi,
    const u16* __restrict__ Alo, float* __restrict__ Dout,
    int ldB, int ldD, long bStrideB, long bStrideD) {
  const int lane = threadIdx.x & 63;
  const int wave = threadIdx.x >> 6;
  const int l15  = lane & 15;
  const int kg   = lane >> 4;           // 0..3 quarter-wave k-group
  const int kq   = kg * 8;              // lane k offset within a 32-k step
  const int n0   = blockIdx.x * 64 + wave * 16 + l15;
  const long bb  = (long)blockIdx.y * bStrideB;
  const long db  = (long)blockIdx.y * bStrideD;
  const float* bp = Bsrc + bb + n0;

  f32x4 acc[13];
#pragma unroll
  for (int t = 0; t < 13; ++t)
#pragma unroll
    for (int q = 0; q < 4; ++q) acc[t][q] = 0.f;

  float xa[8], xb[8];
  LOADB(0, xa)
  LOADB(1, xb)
  MFMA_STAGE(0, xa)
  LOADB(2, xa)
  MFMA_STAGE(1, xb)
  LOADB(3, xb)
  MFMA_STAGE(2, xa)
  LOADB(4, xa)
  MFMA_STAGE(3, xb)
  LOADB(5, xb)
  MFMA_STAGE(4, xa)
  // k-tail: step 6 covers k 192..223; only kg==0 (k 192..199) is real data.
  // A rows are zero-padded for k>=200, so other groups feed zeros.
  if (kg == 0) {
    LOADB(6, xa)
  } else {
#pragma unroll
    for (int e = 0; e < 8; ++e) xa[e] = 0.f;
  }
  MFMA_STAGE(5, xb)
  MFMA_STAGE(6, xa)

#pragma unroll
  for (int t = 0; t < 13; ++t) {
    const int rb = t * 16 + kg * 4;
#pragma unroll
    for (int r = 0; r < 4; ++r) {
      const int row = rb + r;
      if (row < N12) Dout[db + (long)row * ldD + n0] = acc[t][r];
    }
  }
}

// ---------------- fallback path helpers (unused when ws >= 256 MB) ---------
__global__ __launch_bounds__(256) void k_transpose(
    const float* __restrict__ K2, float* __restrict__ K2T) {
  int t = blockIdx.x * 256 + threadIdx.x;
  if (t < N12 * N12) {
    int i = t / N12, a = t % N12;
    K2T[t] = K2[a * N12 + i];
  }
}

__global__ __launch_bounds__(256) void k_contract_j_inplace(
    float* T12, const float* __restrict__ K2T) {
  __shared__ float lds[N12 * 80];   // 64000 B
  const int a    = blockIdx.y;
  const int m0   = blockIdx.x * 80;
  const int base = a * SJK + m0;
  for (int t = threadIdx.x; t < N12 * 80; t += 256) {
    int j = t / 80, ml = t % 80;
    lds[t] = T12[base + j * SKS + ml];
  }
  __syncthreads();
  for (int o = threadIdx.x; o < N12 * 80; o += 256) {
    int b = o / 80, ml = o % 80;
    float acc = 0.f;
#pragma unroll 4
    for (int j = 0; j < N12; ++j)
      acc = fmaf(K2T[j * N12 + b], lds[j * 80 + ml], acc);
    T12[base + b * SKS + ml] = acc;
  }
}

// ------------- gather: out[n,s] = sum_k K3[c,k] * T2[a,b,k,s]  (a,b,c < 50)
__global__ __launch_bounds__(256) void k_gather(
    const float* T2, const float* __restrict__ K3,
    const int* __restrict__ idx, float* __restrict__ out) {
  int g = blockIdx.x * 256 + threadIdx.x;   // 3.2M threads exactly
  int n = g >> 5, s = g & 31;
  int a = idx[n * 3 + 0], b = idx[n * 3 + 1], c = idx[n * 3 + 2];
  const float* t2  = T2 + a * SJK + b * SKS + s;
  const float* k3r = K3 + c * N3;
  float acc = 0.f;
#pragma unroll
  for (int k = 0; k < N3; ++k) acc = fmaf(k3r[k], t2[k * R2], acc);
  out[g] = acc;
}

// ------- contract k + elementwise: reg[a,b,c,s] = (sum_k K3[c,k]*T2[a,b,k,s]) * TT
__global__ __launch_bounds__(256) void k_contract_k_reg(
    const float* T2, const float* __restrict__ TT,
    const float* __restrict__ K3, float* reg) {
  const int t  = blockIdx.x * 256 + threadIdx.x;  // 1.28M threads = 40000*32
  const int s  = t & 31;
  const int ab = t >> 5;                          // 0..39999
  const int base = ab * SKS + s;
  float v[N3];
#pragma unroll
  for (int k = 0; k < N3; ++k) v[k] = T2[base + k * R2];
  for (int c = 0; c < N3; ++c) {
    const float* k3r = K3 + c * N3;               // wave-uniform -> s_load
    float a0 = 0.f, a1 = 0.f, a2 = 0.f, a3 = 0.f;
#pragma unroll
    for (int k = 0; k < 48; k += 4) {
      a0 = fmaf(k3r[k],     v[k],     a0);
      a1 = fmaf(k3r[k + 1], v[k + 1], a1);
      a2 = fmaf(k3r[k + 2], v[k + 2], a2);
      a3 = fmaf(k3r[k + 3], v[k + 3], a3);
    }
    a0 = fmaf(k3r[48], v[48], a0);
    a1 = fmaf(k3r[49], v[49], a1);
    const int o = base + c * R2;
    reg[o] = ((a0 + a1) + (a2 + a3)) * TT[o];
  }
}

extern "C" void kernel_launch(void* const* d_in, const int* in_sizes, int n_in,
                              void* d_out, int out_size, void* d_ws, size_t ws_size,
                              hipStream_t stream) {
  const float* TT  = (const float*)d_in[0];
  const float* K1  = (const float*)d_in[1];
  const float* K2  = (const float*)d_in[2];
  const float* K3  = (const float*)d_in[3];
  const int*   idx = (const int*)d_in[4];

  float* out = (float*)d_out;          // [0, 3.2M)
  float* reg = out + OUT_ELEMS;        // [3.2M, 67.2M) -- also T1 scratch
  // Prepped K hi/lo arrays live at the start of the out region (dead by the
  // time k_gather overwrites every out element).
  u16* khi = (u16*)d_out;                       // 2 * 208*224 ushorts
  u16* klo = khi + 2 * APAD * KPAD;             // 2 * 208*224 ushorts
  const int matoff = APAD * KPAD;               // K2 offset within khi/klo

  k_prep<<<dim3((2 * APAD * KPAD + 255) / 256), 256, 0, stream>>>(K1, K2, khi, klo);

  // contract i: T1[a,m] = sum_i K1[a,i]*TT[i,m]  -> reg region
  k_mfma_contract<<<dim3(SJK / 64, 1), 256, 0, stream>>>(
      TT, khi, klo, reg, SJK, SJK, 0L, 0L);

  const size_t need = (size_t)NTOT * sizeof(float);   // 256,000,000 B
  if (ws_size >= need) {
    float* T2 = (float*)d_ws;
    // contract j (batched over a): T2[a,b,m2] = sum_j K2[b,j]*T1[a,j,m2]
    k_mfma_contract<<<dim3(SKS / 64, N12), 256, 0, stream>>>(
        reg, khi + matoff, klo + matoff, T2, SKS, SKS, (long)SJK, (long)SJK);
    k_gather<<<dim3(OUT_ELEMS / 256), 256, 0, stream>>>(T2, K3, idx, out);
    k_contract_k_reg<<<dim3(40000 * 32 / 256), 256, 0, stream>>>(T2, TT, K3, reg);
  } else {
    // in-place fallback (never taken on this harness: rounds 1-4 ran ws path)
    float* k2t = out + 2 * OUT_ELEMS / 32;  // scratch inside out region
    k_transpose<<<dim3((N12 * N12 + 255) / 256), 256, 0, stream>>>(K2, k2t);
    k_contract_j_inplace<<<dim3(20, N12), 256, 0, stream>>>(reg, k2t);
    k_gather<<<dim3(OUT_ELEMS / 256), 256, 0, stream>>>(reg, K3, idx, out);
    k_contract_k_reg<<<dim3(40000 * 32 / 256), 256, 0, stream>>>(reg, TT, K3, reg);
  }
}

// Round 6
// 687.230 us; speedup vs baseline: 1.3066x; 1.3066x over previous
//
#include <hip/hip_runtime.h>

// Problem constants (from reference):
//   B=100000, R1=1, N1=200, N2=200, N3=50, R2=32
//   TT_core: (1,200,200,50,32) f32  = 64,000,000 elems (256 MB)
//   K1,K2: (200,200) f32; K3: (50,50) f32; indices: (B,3) int (values in [0,50))
//   out = (T3 gathered)[B,1,32] (3.2M f32), reg = T3*TT (64M f32)
// d_out layout: [0,3.2M) out, [3.2M, 67.2M) reg.
//
// Round-6: single-product fp16 MFMA (error ~0.2 << 79.68 threshold; bf16
// comparison floor dominates). Round-5 lesson: hi/lo bf16 split put 26
// L2-latency A-loads per 39 MFMAs on the critical path; fp16 halves A bytes
// (93 KB), cuts per-stage cost to 13 A-loads + 13 MFMA, acc 52 regs ->
// __launch_bounds__(256,4) gives 4 waves/SIMD on the unified VGPR/AGPR file.

typedef float    f32x4 __attribute__((ext_vector_type(4)));
typedef _Float16 half8 __attribute__((ext_vector_type(8)));
typedef unsigned short u16;
typedef unsigned int   u32;

#define N12   200
#define N3    50
#define R2    32
#define SJK   320000          // stride of i in TT == N2*N3*R2; also stride of a in T1
#define SKS   1600            // stride of j / b  == N3*R2
#define NTOT  64000000
#define OUT_ELEMS 3200000     // B*32
#define APAD  208             // padded rows of K matrices (13 * 16)
#define KPAD  224             // padded contraction dim (7 * 32)

// ---------------- prep: convert K1,K2 into padded fp16 [208][224] ----------
// kh holds two matrices back-to-back: K1 at 0, K2 at APAD*KPAD.
__global__ __launch_bounds__(256) void k_prep(
    const float* __restrict__ K1, const float* __restrict__ K2,
    u16* __restrict__ kh) {
  int t = blockIdx.x * 256 + threadIdx.x;
  const int total = APAD * KPAD;
  if (t >= 2 * total) return;
  const float* src = (t < total) ? K1 : K2;
  int tt = (t < total) ? t : t - total;
  int r = tt / KPAD, c = tt % KPAD;
  float x = (r < N12 && c < N12) ? src[r * N12 + c] : 0.f;
  _Float16 h = (_Float16)x;             // v_cvt_f16_f32, RTE
  kh[t] = __builtin_bit_cast(u16, h);
}

// ---------------- MFMA contraction: D[row,n] = sum_k K[row,k] * B[k,n] -----
// A = prepped fp16 [APAD][KPAD], single product. Per wave: n-subtile of 16,
// ALL 13 row-tiles in accumulators; B read once, prefetched depth-1.
// Grids exact (64 | 320000 and 64 | 1600) -> no bounds checks in hot loop.
// MFMA 16x16x32 layouts: A lane: row=l&15, k=(l>>4)*8+e (contiguous);
// B lane: n=l&15, k=(l>>4)*8+e; D lane: col(n)=l&15, row=(l>>4)*4+reg.
#define LOADB(KS, X)                                                         \
  { _Pragma("unroll")                                                        \
    for (int e = 0; e < 8; ++e) X[e] = bp[(long)((KS)*32 + kq + e) * ldB]; }

#define MFMA_STAGE(KS, X)                                                    \
  { half8 bh;                                                                \
    _Pragma("unroll")                                                        \
    for (int e = 0; e < 8; ++e) bh[e] = (_Float16)X[e];                      \
    _Pragma("unroll")                                                        \
    for (int t = 0; t < 13; ++t) {                                           \
      const int aoff = (t * 16 + l15) * KPAD + (KS)*32 + kq;                 \
      half8 ah = *(const half8*)(Ah + aoff);                                 \
      acc[t] = __builtin_amdgcn_mfma_f32_16x16x32_f16(ah, bh, acc[t], 0,0,0); \
    } }

__global__ __launch_bounds__(256, 4) void k_mfma_contract(
    const float* __restrict__ Bsrc, const u16* __restrict__ Ah,
    float* __restrict__ Dout, int ldB, int ldD, long bStrideB, long bStrideD) {
  const int lane = threadIdx.x & 63;
  const int wave = threadIdx.x >> 6;
  const int l15  = lane & 15;
  const int kg   = lane >> 4;           // 0..3 quarter-wave k-group
  const int kq   = kg * 8;              // lane k offset within a 32-k step
  const int n0   = blockIdx.x * 64 + wave * 16 + l15;
  const long bb  = (long)blockIdx.y * bStrideB;
  const long db  = (long)blockIdx.y * bStrideD;
  const float* bp = Bsrc + bb + n0;

  f32x4 acc[13];
#pragma unroll
  for (int t = 0; t < 13; ++t)
#pragma unroll
    for (int q = 0; q < 4; ++q) acc[t][q] = 0.f;

  float xa[8], xb[8];
  LOADB(0, xa)
  LOADB(1, xb)
  MFMA_STAGE(0, xa)
  LOADB(2, xa)
  MFMA_STAGE(1, xb)
  LOADB(3, xb)
  MFMA_STAGE(2, xa)
  LOADB(4, xa)
  MFMA_STAGE(3, xb)
  LOADB(5, xb)
  MFMA_STAGE(4, xa)
  // k-tail: step 6 covers k 192..223; only kg==0 (k 192..199) is real data.
  // A rows are zero-padded for k>=200, so other groups feed zeros.
  if (kg == 0) {
    LOADB(6, xa)
  } else {
#pragma unroll
    for (int e = 0; e < 8; ++e) xa[e] = 0.f;
  }
  MFMA_STAGE(5, xb)
  MFMA_STAGE(6, xa)

#pragma unroll
  for (int t = 0; t < 13; ++t) {
    const int rb = t * 16 + kg * 4;
#pragma unroll
    for (int r = 0; r < 4; ++r) {
      const int row = rb + r;
      if (row < N12) Dout[db + (long)row * ldD + n0] = acc[t][r];
    }
  }
}

// ---------------- fallback path helpers (unused when ws >= 256 MB) ---------
__global__ __launch_bounds__(256) void k_transpose(
    const float* __restrict__ K2, float* __restrict__ K2T) {
  int t = blockIdx.x * 256 + threadIdx.x;
  if (t < N12 * N12) {
    int i = t / N12, a = t % N12;
    K2T[t] = K2[a * N12 + i];
  }
}

__global__ __launch_bounds__(256) void k_contract_j_inplace(
    float* T12, const float* __restrict__ K2T) {
  __shared__ float lds[N12 * 80];   // 64000 B
  const int a    = blockIdx.y;
  const int m0   = blockIdx.x * 80;
  const int base = a * SJK + m0;
  for (int t = threadIdx.x; t < N12 * 80; t += 256) {
    int j = t / 80, ml = t % 80;
    lds[t] = T12[base + j * SKS + ml];
  }
  __syncthreads();
  for (int o = threadIdx.x; o < N12 * 80; o += 256) {
    int b = o / 80, ml = o % 80;
    float acc = 0.f;
#pragma unroll 4
    for (int j = 0; j < N12; ++j)
      acc = fmaf(K2T[j * N12 + b], lds[j * 80 + ml], acc);
    T12[base + b * SKS + ml] = acc;
  }
}

// ------------- gather: out[n,s] = sum_k K3[c,k] * T2[a,b,k,s]  (a,b,c < 50)
__global__ __launch_bounds__(256) void k_gather(
    const float* T2, const float* __restrict__ K3,
    const int* __restrict__ idx, float* __restrict__ out) {
  int g = blockIdx.x * 256 + threadIdx.x;   // 3.2M threads exactly
  int n = g >> 5, s = g & 31;
  int a = idx[n * 3 + 0], b = idx[n * 3 + 1], c = idx[n * 3 + 2];
  const float* t2  = T2 + a * SJK + b * SKS + s;
  const float* k3r = K3 + c * N3;
  float acc = 0.f;
#pragma unroll
  for (int k = 0; k < N3; ++k) acc = fmaf(k3r[k], t2[k * R2], acc);
  out[g] = acc;
}

// ------- contract k + elementwise: reg[a,b,c,s] = (sum_k K3[c,k]*T2[a,b,k,s]) * TT
__global__ __launch_bounds__(256) void k_contract_k_reg(
    const float* T2, const float* __restrict__ TT,
    const float* __restrict__ K3, float* reg) {
  const int t  = blockIdx.x * 256 + threadIdx.x;  // 1.28M threads = 40000*32
  const int s  = t & 31;
  const int ab = t >> 5;                          // 0..39999
  const int base = ab * SKS + s;
  float v[N3];
#pragma unroll
  for (int k = 0; k < N3; ++k) v[k] = T2[base + k * R2];
  for (int c = 0; c < N3; ++c) {
    const float* k3r = K3 + c * N3;               // wave-uniform -> s_load
    float a0 = 0.f, a1 = 0.f, a2 = 0.f, a3 = 0.f;
#pragma unroll
    for (int k = 0; k < 48; k += 4) {
      a0 = fmaf(k3r[k],     v[k],     a0);
      a1 = fmaf(k3r[k + 1], v[k + 1], a1);
      a2 = fmaf(k3r[k + 2], v[k + 2], a2);
      a3 = fmaf(k3r[k + 3], v[k + 3], a3);
    }
    a0 = fmaf(k3r[48], v[48], a0);
    a1 = fmaf(k3r[49], v[49], a1);
    const int o = base + c * R2;
    reg[o] = ((a0 + a1) + (a2 + a3)) * TT[o];
  }
}

extern "C" void kernel_launch(void* const* d_in, const int* in_sizes, int n_in,
                              void* d_out, int out_size, void* d_ws, size_t ws_size,
                              hipStream_t stream) {
  const float* TT  = (const float*)d_in[0];
  const float* K1  = (const float*)d_in[1];
  const float* K2  = (const float*)d_in[2];
  const float* K3  = (const float*)d_in[3];
  const int*   idx = (const int*)d_in[4];

  float* out = (float*)d_out;          // [0, 3.2M)
  float* reg = out + OUT_ELEMS;        // [3.2M, 67.2M) -- also T1 scratch
  // Prepped fp16 K matrices live at the start of the out region (dead by the
  // time k_gather overwrites every out element).
  u16* kh = (u16*)d_out;                        // 2 * 208*224 ushorts
  const int matoff = APAD * KPAD;               // K2 offset within kh

  k_prep<<<dim3((2 * APAD * KPAD + 255) / 256), 256, 0, stream>>>(K1, K2, kh);

  // contract i: T1[a,m] = sum_i K1[a,i]*TT[i,m]  -> reg region
  k_mfma_contract<<<dim3(SJK / 64, 1), 256, 0, stream>>>(
      TT, kh, reg, SJK, SJK, 0L, 0L);

  const size_t need = (size_t)NTOT * sizeof(float);   // 256,000,000 B
  if (ws_size >= need) {
    float* T2 = (float*)d_ws;
    // contract j (batched over a): T2[a,b,m2] = sum_j K2[b,j]*T1[a,j,m2]
    k_mfma_contract<<<dim3(SKS / 64, N12), 256, 0, stream>>>(
        reg, kh + matoff, T2, SKS, SKS, (long)SJK, (long)SJK);
    k_gather<<<dim3(OUT_ELEMS / 256), 256, 0, stream>>>(T2, K3, idx, out);
    k_contract_k_reg<<<dim3(40000 * 32 / 256), 256, 0, stream>>>(T2, TT, K3, reg);
  } else {
    // in-place fallback (never taken on this harness: rounds 1-5 ran ws path)
    float* k2t = out + 2 * OUT_ELEMS / 32;  // scratch inside out region
    k_transpose<<<dim3((N12 * N12 + 255) / 256), 256, 0, stream>>>(K2, k2t);
    k_contract_j_inplace<<<dim3(20, N12), 256, 0, stream>>>(reg, k2t);
    k_gather<<<dim3(OUT_ELEMS / 256), 256, 0, stream>>>(reg, K3, idx, out);
    k_contract_k_reg<<<dim3(40000 * 32 / 256), 256, 0, stream>>>(reg, TT, K3, reg);
  }
}

// Round 7
// 506.054 us; speedup vs baseline: 1.7744x; 1.3580x over previous
//
#include <hip/hip_runtime.h>

// Problem constants (from reference):
//   B=100000, R1=1, N1=200, N2=200, N3=50, R2=32
//   TT_core: (1,200,200,50,32) f32  = 64,000,000 elems (256 MB)
//   K1,K2: (200,200) f32; K3: (50,50) f32; indices: (B,3) int (values in [0,50))
//   out = (T3 gathered)[B,1,32] (3.2M f32), reg = T3*TT (64M f32)
// d_out layout: [0,3.2M) out, [3.2M, 67.2M) reg.
//
// Round-7: decouple A/B load streams (round-6 evidence: per-stage ~12k cyc =
// in-order vmcnt queue makes every A-fragment wait imply waiting for the NEXT
// stage's 8 HBM B-loads -> pipeline structurally dead).
//   - A (small fp16 K-matrix) -> LDS double-buffer (reg-staged), MFMA A-reads
//     become ds_read_b128 on lgkmcnt, decoupled from vmcnt.
//   - B -> ALL 56 dword loads issued in prologue into named f32x8 regs; one
//     drain at first barrier; k-row clamp to 199 (A zero-pad kills garbage).

typedef float    f32x4 __attribute__((ext_vector_type(4)));
typedef float    f32x8 __attribute__((ext_vector_type(8)));
typedef _Float16 half8 __attribute__((ext_vector_type(8)));
typedef unsigned short u16;
typedef unsigned int   u32;

#define N12   200
#define N3    50
#define R2    32
#define SJK   320000          // stride of i in TT == N2*N3*R2; also stride of a in T1
#define SKS   1600            // stride of j / b  == N3*R2
#define NTOT  64000000
#define OUT_ELEMS 3200000     // B*32
#define APAD  208             // padded rows of K matrices (13 * 16)
#define KPAD  224             // padded contraction dim (7 * 32)

// ---------------- prep: convert K1,K2 into padded fp16 [208][224] ----------
__global__ __launch_bounds__(256) void k_prep(
    const float* __restrict__ K1, const float* __restrict__ K2,
    u16* __restrict__ kh) {
  int t = blockIdx.x * 256 + threadIdx.x;
  const int total = APAD * KPAD;
  if (t >= 2 * total) return;
  const float* src = (t < total) ? K1 : K2;
  int tt = (t < total) ? t : t - total;
  int r = tt / KPAD, c = tt % KPAD;
  float x = (r < N12 && c < N12) ? src[r * N12 + c] : 0.f;
  _Float16 h = (_Float16)x;             // v_cvt_f16_f32, RTE
  kh[t] = __builtin_bit_cast(u16, h);
}

// ---------------- MFMA contraction: D[row,n] = sum_k K[row,k] * B[k,n] -----
// A-slice (one 32-k step, all 208 rows, fp16 = 13312 B) lives in LDS dbuf.
// Chunk c = wave*4+i covers rows c*16..c*16+15; lane l -> row c*16+(l>>2),
// col-halves (l&3)*8; LDS linear As[buf][c*512 + l*8] == row-major [256][32].
// Rows 208..255 are staging overrun (reads stay inside d_out; never ds_read).
// ds_read pattern: 16B granules tile all 32 banks -> conflict-free.

#define ALOAD(S)                                                              \
  { ar0 = *(const int4*)(Ah + ((wave*4+0)*16 + arow) * KPAD + (S)*32 + acolh); \
    ar1 = *(const int4*)(Ah + ((wave*4+1)*16 + arow) * KPAD + (S)*32 + acolh); \
    ar2 = *(const int4*)(Ah + ((wave*4+2)*16 + arow) * KPAD + (S)*32 + acolh); \
    ar3 = *(const int4*)(Ah + ((wave*4+3)*16 + arow) * KPAD + (S)*32 + acolh); }

#define ASTORE(BUF)                                                           \
  { *(int4*)(&As[BUF][(wave*4+0)*512 + lane*8]) = ar0;                        \
    *(int4*)(&As[BUF][(wave*4+1)*512 + lane*8]) = ar1;                        \
    *(int4*)(&As[BUF][(wave*4+2)*512 + lane*8]) = ar2;                        \
    *(int4*)(&As[BUF][(wave*4+3)*512 + lane*8]) = ar3; }

#define LOADB(S, BV)                                                          \
  { _Pragma("unroll")                                                         \
    for (int e = 0; e < 8; ++e) {                                             \
      int kr = (S)*32 + kq + e; if (kr > 199) kr = 199;                       \
      BV[e] = bp[(long)kr * ldB]; } }

#define STAGE(S, BV)                                                          \
  { half8 bh;                                                                 \
    _Pragma("unroll")                                                         \
    for (int e = 0; e < 8; ++e) bh[e] = (_Float16)BV[e];                      \
    const u16* as_ = &As[(S)&1][0];                                           \
    _Pragma("unroll")                                                         \
    for (int t = 0; t < 13; ++t) {                                            \
      half8 ah = *(const half8*)(as_ + (t*16 + l15)*32 + kq);                 \
      acc[t] = __builtin_amdgcn_mfma_f32_16x16x32_f16(ah, bh, acc[t], 0,0,0); \
    } }

__global__ __launch_bounds__(256, 3) void k_mfma_contract(
    const float* __restrict__ Bsrc, const u16* __restrict__ Ah,
    float* __restrict__ Dout, int ldB, int ldD, long bStrideB, long bStrideD) {
  __shared__ __align__(16) u16 As[2][8192];   // 2 x 16 KB
  const int lane = threadIdx.x & 63;
  const int wave = threadIdx.x >> 6;
  const int l15  = lane & 15;
  const int kg   = lane >> 4;
  const int kq   = kg * 8;
  const int arow = lane >> 2;           // 0..15 within a 16-row chunk
  const int acolh = (lane & 3) * 8;     // halves
  const int n0   = blockIdx.x * 64 + wave * 16 + l15;
  const long bb  = (long)blockIdx.y * bStrideB;
  const long db  = (long)blockIdx.y * bStrideD;
  const float* bp = Bsrc + bb + n0;

  f32x4 acc[13];
#pragma unroll
  for (int t = 0; t < 13; ++t)
#pragma unroll
    for (int q = 0; q < 4; ++q) acc[t][q] = 0.f;

  int4 ar0, ar1, ar2, ar3;
  f32x8 B0, B1, B2, B3, B4, B5, B6;

  // prologue: A-slice 0 + ALL B loads; single drain at first barrier
  ALOAD(0)
  LOADB(0, B0) LOADB(1, B1) LOADB(2, B2) LOADB(3, B3)
  LOADB(4, B4) LOADB(5, B5) LOADB(6, B6)
  ASTORE(0)
  __syncthreads();

  ALOAD(1)  STAGE(0, B0)  ASTORE(1)  __syncthreads();
  ALOAD(2)  STAGE(1, B1)  ASTORE(0)  __syncthreads();
  ALOAD(3)  STAGE(2, B2)  ASTORE(1)  __syncthreads();
  ALOAD(4)  STAGE(3, B3)  ASTORE(0)  __syncthreads();
  ALOAD(5)  STAGE(4, B4)  ASTORE(1)  __syncthreads();
  ALOAD(6)  STAGE(5, B5)  ASTORE(0)  __syncthreads();
  STAGE(6, B6)

#pragma unroll
  for (int t = 0; t < 13; ++t) {
    const int rb = t * 16 + kg * 4;
#pragma unroll
    for (int r = 0; r < 4; ++r) {
      const int row = rb + r;
      if (row < N12) Dout[db + (long)row * ldD + n0] = acc[t][r];
    }
  }
}

// ---------------- fallback path helpers (unused when ws >= 256 MB) ---------
__global__ __launch_bounds__(256) void k_transpose(
    const float* __restrict__ K2, float* __restrict__ K2T) {
  int t = blockIdx.x * 256 + threadIdx.x;
  if (t < N12 * N12) {
    int i = t / N12, a = t % N12;
    K2T[t] = K2[a * N12 + i];
  }
}

__global__ __launch_bounds__(256) void k_contract_j_inplace(
    float* T12, const float* __restrict__ K2T) {
  __shared__ float lds[N12 * 80];   // 64000 B
  const int a    = blockIdx.y;
  const int m0   = blockIdx.x * 80;
  const int base = a * SJK + m0;
  for (int t = threadIdx.x; t < N12 * 80; t += 256) {
    int j = t / 80, ml = t % 80;
    lds[t] = T12[base + j * SKS + ml];
  }
  __syncthreads();
  for (int o = threadIdx.x; o < N12 * 80; o += 256) {
    int b = o / 80, ml = o % 80;
    float acc = 0.f;
#pragma unroll 4
    for (int j = 0; j < N12; ++j)
      acc = fmaf(K2T[j * N12 + b], lds[j * 80 + ml], acc);
    T12[base + b * SKS + ml] = acc;
  }
}

// ------------- gather: out[n,s] = sum_k K3[c,k] * T2[a,b,k,s]  (a,b,c < 50)
__global__ __launch_bounds__(256) void k_gather(
    const float* T2, const float* __restrict__ K3,
    const int* __restrict__ idx, float* __restrict__ out) {
  int g = blockIdx.x * 256 + threadIdx.x;   // 3.2M threads exactly
  int n = g >> 5, s = g & 31;
  int a = idx[n * 3 + 0], b = idx[n * 3 + 1], c = idx[n * 3 + 2];
  const float* t2  = T2 + a * SJK + b * SKS + s;
  const float* k3r = K3 + c * N3;
  float acc = 0.f;
#pragma unroll
  for (int k = 0; k < N3; ++k) acc = fmaf(k3r[k], t2[k * R2], acc);
  out[g] = acc;
}

// ------- contract k + elementwise: reg[a,b,c,s] = (sum_k K3[c,k]*T2[a,b,k,s]) * TT
__global__ __launch_bounds__(256) void k_contract_k_reg(
    const float* T2, const float* __restrict__ TT,
    const float* __restrict__ K3, float* reg) {
  const int t  = blockIdx.x * 256 + threadIdx.x;  // 1.28M threads = 40000*32
  const int s  = t & 31;
  const int ab = t >> 5;                          // 0..39999
  const int base = ab * SKS + s;
  float v[N3];
#pragma unroll
  for (int k = 0; k < N3; ++k) v[k] = T2[base + k * R2];
  for (int c = 0; c < N3; ++c) {
    const float* k3r = K3 + c * N3;               // wave-uniform -> s_load
    float a0 = 0.f, a1 = 0.f, a2 = 0.f, a3 = 0.f;
#pragma unroll
    for (int k = 0; k < 48; k += 4) {
      a0 = fmaf(k3r[k],     v[k],     a0);
      a1 = fmaf(k3r[k + 1], v[k + 1], a1);
      a2 = fmaf(k3r[k + 2], v[k + 2], a2);
      a3 = fmaf(k3r[k + 3], v[k + 3], a3);
    }
    a0 = fmaf(k3r[48], v[48], a0);
    a1 = fmaf(k3r[49], v[49], a1);
    const int o = base + c * R2;
    reg[o] = ((a0 + a1) + (a2 + a3)) * TT[o];
  }
}

extern "C" void kernel_launch(void* const* d_in, const int* in_sizes, int n_in,
                              void* d_out, int out_size, void* d_ws, size_t ws_size,
                              hipStream_t stream) {
  const float* TT  = (const float*)d_in[0];
  const float* K1  = (const float*)d_in[1];
  const float* K2  = (const float*)d_in[2];
  const float* K3  = (const float*)d_in[3];
  const int*   idx = (const int*)d_in[4];

  float* out = (float*)d_out;          // [0, 3.2M)
  float* reg = out + OUT_ELEMS;        // [3.2M, 67.2M) -- also T1 scratch
  // Prepped fp16 K matrices live at the start of the out region (dead by the
  // time k_gather overwrites every out element). A-staging overruns read a
  // few KB past kh -- still inside d_out, benign.
  u16* kh = (u16*)d_out;                        // 2 * 208*224 ushorts
  const int matoff = APAD * KPAD;               // K2 offset within kh

  k_prep<<<dim3((2 * APAD * KPAD + 255) / 256), 256, 0, stream>>>(K1, K2, kh);

  // contract i: T1[a,m] = sum_i K1[a,i]*TT[i,m]  -> reg region
  k_mfma_contract<<<dim3(SJK / 64, 1), 256, 0, stream>>>(
      TT, kh, reg, SJK, SJK, 0L, 0L);

  const size_t need = (size_t)NTOT * sizeof(float);   // 256,000,000 B
  if (ws_size >= need) {
    float* T2 = (float*)d_ws;
    // contract j (batched over a): T2[a,b,m2] = sum_j K2[b,j]*T1[a,j,m2]
    k_mfma_contract<<<dim3(SKS / 64, N12), 256, 0, stream>>>(
        reg, kh + matoff, T2, SKS, SKS, (long)SJK, (long)SJK);
    k_gather<<<dim3(OUT_ELEMS / 256), 256, 0, stream>>>(T2, K3, idx, out);
    k_contract_k_reg<<<dim3(40000 * 32 / 256), 256, 0, stream>>>(T2, TT, K3, reg);
  } else {
    // in-place fallback (never taken on this harness: rounds 1-6 ran ws path)
    float* k2t = out + 2 * OUT_ELEMS / 32;  // scratch inside out region
    k_transpose<<<dim3((N12 * N12 + 255) / 256), 256, 0, stream>>>(K2, k2t);
    k_contract_j_inplace<<<dim3(20, N12), 256, 0, stream>>>(reg, k2t);
    k_gather<<<dim3(OUT_ELEMS / 256), 256, 0, stream>>>(reg, K3, idx, out);
    k_contract_k_reg<<<dim3(40000 * 32 / 256), 256, 0, stream>>>(reg, TT, K3, reg);
  }
}